// Round 11
// baseline (222.918 us; speedup 1.0000x reference)
//
#include <hip/hip_runtime.h>
#include <hip/hip_bf16.h>
#include <math.h>

// Problem constants (B, N, D) = (256, 128, 128)
#define B_    256
#define N_    128
#define MAXP  30
#define OTHER_ 35
#define CIN1  131
#define NIDX  381

#define KPAD1 160
#define KPAD2 256
#define KPAD3 128
#define S_IDX (B_ * NIDX)          // 97536
#define S_P1  (15 * 16 * 512)      // 122880  (gks * SUB16 * 512)
#define S_P2  (24 * 8 * 512)       // 98304
#define S_P3  (12 * 4 * 512)       // 24576
#define PREP_TOTAL (S_IDX + S_P1 + S_P2 + S_P3)
#define PREP_BLOCKS ((PREP_TOTAL + 511) / 512)
#define EMBED_BLOCKS (B_ * 4)

typedef short short8 __attribute__((ext_vector_type(8)));
typedef float f32x4 __attribute__((ext_vector_type(4)));

// RNE split of f32 into hi/lo bf16 via bit math (prep only)
__device__ inline void split1(float v, short& h, short& l) {
  unsigned u = __float_as_uint(v);
  unsigned hb = (u + 0x7fffu + ((u >> 16) & 1u)) >> 16;
  float fh = __uint_as_float(hb << 16);
  float r = v - fh;
  unsigned u2 = __float_as_uint(r);
  unsigned lb = (u2 + 0x7fffu + ((u2 >> 16) & 1u)) >> 16;
  h = (short)hb;
  l = (short)lb;
}

// RNE split via HW cvt — hot path
__device__ inline void split2(float v, short& h, short& l) {
  __hip_bfloat16 hb = __float2bfloat16(v);
  float fh = __bfloat162float(hb);
  __hip_bfloat16 lb = __float2bfloat16(v - fh);
  __builtin_memcpy(&h, &hb, 2);
  __builtin_memcpy(&l, &lb, 2);
}

// ---------------------------------------------------------------------------
// Weight pack (NWO=1): l -> [gks][su][lane][e]; oc = su*16+(lane&15),
// ctot = gks*32 + ((lane>>4)&3)*8 + e; kk = ctot/KPAD, ch = ctot%KPAD.
// ---------------------------------------------------------------------------
template <int KREAL, int KPAD, int SUB>
__device__ inline void packw(int l, const float* __restrict__ w,
                             short* __restrict__ oh, short* __restrict__ ol) {
  const int e = l & 7;
  const int lane = (l >> 3) & 63;
  const int x = l >> 9;
  const int su = x % SUB;
  const int gks = x / SUB;
  const int oc = su * 16 + (lane & 15);
  const int ctot = gks * 32 + ((lane >> 4) & 3) * 8 + e;
  const int kk = ctot / KPAD;
  const int ch = ctot - kk * KPAD;
  const float v = (ch < KREAL) ? w[(oc * KREAL + ch) * 3 + kk] : 0.f;
  short h, lo;
  split1(v, h, lo);
  oh[l] = h;
  ol[l] = lo;
}

// ---------------------------------------------------------------------------
// Merged prep + embed (same as r10, NWO=1 packs).
// ---------------------------------------------------------------------------
__global__ __launch_bounds__(512) void prep_embed_kernel(
    const float* __restrict__ feature,
    const float* __restrict__ col_embed,   // (200,32)
    const float* __restrict__ op_embed,    // (20,32)
    short* __restrict__ collateH, short* __restrict__ collateL,
    const void* __restrict__ rawIdx, int* __restrict__ idx32,
    const float* __restrict__ w1, short* __restrict__ w1h, short* __restrict__ w1l,
    const float* __restrict__ w2, short* __restrict__ w2h, short* __restrict__ w2l,
    const float* __restrict__ w3, short* __restrict__ w3h, short* __restrict__ w3l) {
  const int bx = blockIdx.x;
  const int tid = threadIdx.x;

  if (bx >= EMBED_BLOCKS) {
    const int gid = (bx - EMBED_BLOCKS) * 512 + tid;
    if (gid < S_IDX) {
      // int64 LE view is (v,0,v,0,...) with v in [0,128)
      const int* r32 = (const int*)rawIdx;
      const int lane = tid & 63;
      const int lo = r32[2 * lane];
      const int hi = r32[2 * lane + 1];
      const bool ok = (hi == 0 && lo >= 0 && lo < N_);
      const bool is64 = __all(ok);
      idx32[gid] = is64 ? (int)((const long long*)rawIdx)[gid] : ((const int*)rawIdx)[gid];
    } else if (gid < S_IDX + S_P1) {
      packw<131, KPAD1, 16>(gid - S_IDX, w1, w1h, w1l);
    } else if (gid < S_IDX + S_P1 + S_P2) {
      packw<256, KPAD2, 8>(gid - (S_IDX + S_P1), w2, w2h, w2l);
    } else if (gid < PREP_TOTAL) {
      packw<128, KPAD3, 4>(gid - (S_IDX + S_P1 + S_P2), w3, w3h, w3l);
    }
    return;
  }

  __shared__ float feat[128 * 33];
  __shared__ float ce[200 * 32];
  __shared__ float oe[20 * 32];
  const int b = bx >> 2;
  const int n0 = (bx & 3) * 32;
  const float* fb = feature + (size_t)b * 16384;

  {
    const float4* s = (const float4*)col_embed;
    float4* d = (float4*)ce;
#pragma unroll
    for (int it = 0; it < 4; ++it) {
      const int t = it * 512 + tid;
      if (t < 1600) d[t] = s[t];
    }
    if (tid < 160) ((float4*)oe)[tid] = ((const float4*)op_embed)[tid];
  }
  {
    const int d = tid >> 2;
    const int c8 = (tid & 3) * 8;
    const float4 v0 = *reinterpret_cast<const float4*>(&fb[d * 128 + n0 + c8]);
    const float4 v1 = *reinterpret_cast<const float4*>(&fb[d * 128 + n0 + c8 + 4]);
    float* p = &feat[d * 33 + c8];
    p[0] = v0.x; p[1] = v0.y; p[2] = v0.z; p[3] = v0.w;
    p[4] = v1.x; p[5] = v1.y; p[6] = v1.z; p[7] = v1.w;
  }
  __syncthreads();

  const int wv = tid >> 6;
  const int lane = tid & 63;
  const int cl = lane & 31;

#pragma unroll
  for (int ni = 0; ni < 4; ++ni) {
    const int nl = wv * 4 + ni;
    const int n = n0 + nl;
    int civ = 0, oiv = 0;
    if (lane < MAXP) civ = (int)feat[(OTHER_ + lane) * 33 + nl];
    if (lane >= 32 && lane < 32 + MAXP) oiv = (int)feat[(OTHER_ + MAXP + (lane - 32)) * 33 + nl];
    const int L = (int)feat[95 * 33 + nl];

    float acc = 0.f;
    for (int i = 0; i < L; ++i) {
      const int cv = __shfl(civ, i);
      const int ov = __shfl(oiv, 32 + i);
      acc += (lane < 32) ? ce[cv * 32 + cl] : oe[ov * 32 + cl];
    }

    short* outH = collateH + ((size_t)b * 128 + n) * KPAD1;
    short* outL = collateL + ((size_t)b * 128 + n) * KPAD1;
    short h, l;
    split2(acc, h, l);
    outH[35 + lane] = h; outL[35 + lane] = l;
    if (lane < 35) {
      split2(feat[lane * 33 + nl], h, l);
      outH[lane] = h; outL[lane] = l;
    }
    if (lane < 32) {
      split2(feat[(96 + lane) * 33 + nl], h, l);
      outH[99 + lane] = h; outL[99 + lane] = l;
    }
    if (lane < 29) { outH[131 + lane] = 0; outL[131 + lane] = 0; }
  }
}

// ---------------------------------------------------------------------------
// FUSED conv1+norm+conv2+norm+conv3+norm+maxpool+MLP.
// Block = one batch (grid 256), 512 threads = 8 waves. Wave w owns j-tile
// [w*16, w*16+16) and ALL output channels (SUB = COUT/16): per gks only 2
// A-LDS reads feed 3*SUB MFMAs (LDS no longer the bottleneck); all waves
// read the same weight fragments (L1 broadcast). Layer outputs stay in
// registers (a1 64, a2 32, a3 16 f32/thread); inter-layer LDS staging is
// written from registers (norm+leaky+split at write time).
// ---------------------------------------------------------------------------
__global__ __launch_bounds__(512, 1) void fused_kernel(
    const short* __restrict__ XH, const short* __restrict__ XL,  // collate
    const int* __restrict__ idx,
    const short* __restrict__ w1h, const short* __restrict__ w1l,
    const short* __restrict__ w2h, const short* __restrict__ w2l,
    const short* __restrict__ w3h, const short* __restrict__ w3l,
    const float* __restrict__ b1, const float* __restrict__ b2,
    const float* __restrict__ b3,
    const float* __restrict__ fw1, const float* __restrict__ fb1,
    const float* __restrict__ fw2, const float* __restrict__ fb2,
    float* __restrict__ out) {
  constexpr int CINP = 72;

  __shared__ short sH[128 * CINP];
  __shared__ short sL[128 * CINP];
  __shared__ int nb_s[NIDX];
  __shared__ double red[16];
  __shared__ float bc[2];
  __shared__ float poolw[8][64];

  const int b = blockIdx.x;
  const int tid = threadIdx.x;
  const int lane = tid & 63;
  const int w = tid >> 6;
  const int col = lane & 15;
  const int grp = (lane >> 4) & 3;
  const int jA = w * 16 + col;          // A-fragment row (gather source j)
  const int jC = w * 16 + grp * 4;      // C row base (output j = jC + r)

  const short8* __restrict__ wp1h = (const short8*)w1h;
  const short8* __restrict__ wp1l = (const short8*)w1l;
  const short8* __restrict__ wp2h = (const short8*)w2h;
  const short8* __restrict__ wp2l = (const short8*)w2l;
  const short8* __restrict__ wp3h = (const short8*)w3h;
  const short8* __restrict__ wp3l = (const short8*)w3l;

  // ---------------- conv1: stage collate (PURE copy), 3 stages of <=64 ch --
  const short* __restrict__ XHb = XH + (size_t)b * (128 * KPAD1);
  const short* __restrict__ XLb = XL + (size_t)b * (128 * KPAD1);
  short8 rh[2], rl[2];

  auto LOADS1 = [&](int s) {
    const int chb = s * 64;
    const int chn = (KPAD1 - chb < 64) ? (KPAD1 - chb) : 64;
    const int PKs = chn / 8;
#pragma unroll
    for (int it = 0; it < 2; ++it) {
      const int t = it * 512 + tid;
      if (t < 128 * PKs) {
        const int n = t / PKs;
        const int ch0 = chb + (t - n * PKs) * 8;
        rh[it] = *reinterpret_cast<const short8*>(&XHb[n * KPAD1 + ch0]);
        rl[it] = *reinterpret_cast<const short8*>(&XLb[n * KPAD1 + ch0]);
      }
    }
  };
  auto WRITES1 = [&](int s) {
    const int chb = s * 64;
    const int chn = (KPAD1 - chb < 64) ? (KPAD1 - chb) : 64;
    const int PKs = chn / 8;
#pragma unroll
    for (int it = 0; it < 2; ++it) {
      const int t = it * 512 + tid;
      if (t < 128 * PKs) {
        const int n = t / PKs;
        const int c0 = (t - n * PKs) * 8;
        *reinterpret_cast<short8*>(&sH[n * CINP + c0]) = rh[it];
        *reinterpret_cast<short8*>(&sL[n * CINP + c0]) = rl[it];
      }
    }
  };

  auto blockStats = [&](double ss, double sq, double cnt) {
#pragma unroll
    for (int o = 32; o > 0; o >>= 1) {
      ss += __shfl_down(ss, o, 64);
      sq += __shfl_down(sq, o, 64);
    }
    if (lane == 0) { red[w * 2] = ss; red[w * 2 + 1] = sq; }
    __syncthreads();
    if (tid == 0) {
      double S = 0.0, Q = 0.0;
#pragma unroll
      for (int i = 0; i < 8; ++i) { S += red[i * 2]; Q += red[i * 2 + 1]; }
      const double m = S / cnt;
      double var = (Q - S * S / cnt) / (cnt - 1.0);
      if (var < 0.0) var = 0.0;
      bc[0] = (float)m;
      bc[1] = (float)(1.0 / (sqrt(var) + 1e-5));
    }
    __syncthreads();
  };

  f32x4 a1[16];
#pragma unroll
  for (int su = 0; su < 16; ++su) {
    a1[su][0] = 0.f; a1[su][1] = 0.f; a1[su][2] = 0.f; a1[su][3] = 0.f;
  }

  LOADS1(0);
  if (tid < NIDX) nb_s[tid] = idx[b * NIDX + tid];
  WRITES1(0);
  __syncthreads();

  int nbr[3];
#pragma unroll
  for (int kk = 0; kk < 3; ++kk)
    nbr[kk] = (jA > 0) ? nb_s[(jA - 1) * 3 + kk] : 0;

#pragma unroll
  for (int s = 0; s < 3; ++s) {
    if (s < 2) LOADS1(s + 1);
    const int nq = (s == 2) ? 1 : 2;
#pragma unroll
    for (int kk = 0; kk < 3; ++kk) {
      for (int q = 0; q < nq; ++q) {
        const int gks = kk * 5 + s * 2 + q;
        const int ei = nbr[kk] * CINP + q * 32 + grp * 8;
        const short8 ah = *reinterpret_cast<const short8*>(&sH[ei]);
        const short8 al = *reinterpret_cast<const short8*>(&sL[ei]);
#pragma unroll
        for (int sc = 0; sc < 2; ++sc) {
          short8 bh[8], bl[8];
#pragma unroll
          for (int u = 0; u < 8; ++u) {
            const int wi = (gks * 16 + sc * 8 + u) * 64 + lane;
            bh[u] = wp1h[wi];
            bl[u] = wp1l[wi];
          }
#pragma unroll
          for (int u = 0; u < 8; ++u) {
            const int su = sc * 8 + u;
            a1[su] = __builtin_amdgcn_mfma_f32_16x16x32_bf16(ah, bh[u], a1[su], 0, 0, 0);
            a1[su] = __builtin_amdgcn_mfma_f32_16x16x32_bf16(al, bh[u], a1[su], 0, 0, 0);
            a1[su] = __builtin_amdgcn_mfma_f32_16x16x32_bf16(ah, bl[u], a1[su], 0, 0, 0);
          }
        }
      }
    }
    if (s < 2) {
      __syncthreads();
      WRITES1(s + 1);
      __syncthreads();
    }
  }

  // ---- epilogue1: bias, zero col j=0, stats ----
  {
    double ss = 0.0, sq = 0.0;
#pragma unroll
    for (int su = 0; su < 16; ++su) {
      const float bv = b1[su * 16 + col];
#pragma unroll
      for (int r = 0; r < 4; ++r) {
        const int j = jC + r;
        const float val = (j > 0) ? a1[su][r] + bv : 0.f;
        a1[su][r] = val;
        ss += (double)val;
        sq += (double)val * (double)val;
      }
    }
    blockStats(ss, sq, 256.0 * 128.0);
  }
  const float mean1 = bc[0], inv1 = bc[1];

  // ---------------- conv2: input = norm(Y1) from registers ----------------
  f32x4 a2[8];
#pragma unroll
  for (int su = 0; su < 8; ++su) {
    a2[su][0] = 0.f; a2[su][1] = 0.f; a2[su][2] = 0.f; a2[su][3] = 0.f;
  }

#pragma unroll
  for (int s = 0; s < 4; ++s) {
    __syncthreads();   // prior stage readers done
    // write stage s: channels [64s, 64s+64) = su1 in [4s, 4s+4)
#pragma unroll
    for (int u = 0; u < 4; ++u) {
      const int su = s * 4 + u;
#pragma unroll
      for (int r = 0; r < 4; ++r) {
        const int j = jC + r;
        float v = (a1[su][r] - mean1) * inv1;
        v = fmaxf(v, 0.01f * v);
        short h, l;
        split2(v, h, l);
        const int c = u * 16 + col;
        sH[j * CINP + c] = h;
        sL[j * CINP + c] = l;
      }
    }
    __syncthreads();
#pragma unroll
    for (int kk = 0; kk < 3; ++kk) {
#pragma unroll
      for (int q = 0; q < 2; ++q) {
        const int gks = kk * 8 + s * 2 + q;
        const int ei = nbr[kk] * CINP + q * 32 + grp * 8;
        const short8 ah = *reinterpret_cast<const short8*>(&sH[ei]);
        const short8 al = *reinterpret_cast<const short8*>(&sL[ei]);
        short8 bh[8], bl[8];
#pragma unroll
        for (int u = 0; u < 8; ++u) {
          const int wi = (gks * 8 + u) * 64 + lane;
          bh[u] = wp2h[wi];
          bl[u] = wp2l[wi];
        }
#pragma unroll
        for (int u = 0; u < 8; ++u) {
          a2[u] = __builtin_amdgcn_mfma_f32_16x16x32_bf16(ah, bh[u], a2[u], 0, 0, 0);
          a2[u] = __builtin_amdgcn_mfma_f32_16x16x32_bf16(al, bh[u], a2[u], 0, 0, 0);
          a2[u] = __builtin_amdgcn_mfma_f32_16x16x32_bf16(ah, bl[u], a2[u], 0, 0, 0);
        }
      }
    }
  }

  // ---- epilogue2 ----
  {
    double ss = 0.0, sq = 0.0;
#pragma unroll
    for (int su = 0; su < 8; ++su) {
      const float bv = b2[su * 16 + col];
#pragma unroll
      for (int r = 0; r < 4; ++r) {
        const int j = jC + r;
        const float val = (j > 0) ? a2[su][r] + bv : 0.f;
        a2[su][r] = val;
        ss += (double)val;
        sq += (double)val * (double)val;
      }
    }
    blockStats(ss, sq, 128.0 * 128.0);
  }
  const float mean2 = bc[0], inv2 = bc[1];

  // ---------------- conv3 ----------------
  f32x4 a3[4];
#pragma unroll
  for (int su = 0; su < 4; ++su) {
    a3[su][0] = 0.f; a3[su][1] = 0.f; a3[su][2] = 0.f; a3[su][3] = 0.f;
  }

#pragma unroll
  for (int s = 0; s < 2; ++s) {
    __syncthreads();
#pragma unroll
    for (int u = 0; u < 4; ++u) {
      const int su = s * 4 + u;
#pragma unroll
      for (int r = 0; r < 4; ++r) {
        const int j = jC + r;
        float v = (a2[su][r] - mean2) * inv2;
        v = fmaxf(v, 0.01f * v);
        short h, l;
        split2(v, h, l);
        const int c = u * 16 + col;
        sH[j * CINP + c] = h;
        sL[j * CINP + c] = l;
      }
    }
    __syncthreads();
#pragma unroll
    for (int kk = 0; kk < 3; ++kk) {
#pragma unroll
      for (int q = 0; q < 2; ++q) {
        const int gks = kk * 4 + s * 2 + q;
        const int ei = nbr[kk] * CINP + q * 32 + grp * 8;
        const short8 ah = *reinterpret_cast<const short8*>(&sH[ei]);
        const short8 al = *reinterpret_cast<const short8*>(&sL[ei]);
        short8 bh[4], bl[4];
#pragma unroll
        for (int u = 0; u < 4; ++u) {
          const int wi = (gks * 4 + u) * 64 + lane;
          bh[u] = wp3h[wi];
          bl[u] = wp3l[wi];
        }
#pragma unroll
        for (int u = 0; u < 4; ++u) {
          a3[u] = __builtin_amdgcn_mfma_f32_16x16x32_bf16(ah, bh[u], a3[u], 0, 0, 0);
          a3[u] = __builtin_amdgcn_mfma_f32_16x16x32_bf16(al, bh[u], a3[u], 0, 0, 0);
          a3[u] = __builtin_amdgcn_mfma_f32_16x16x32_bf16(ah, bl[u], a3[u], 0, 0, 0);
        }
      }
    }
  }

  // ---- epilogue3 + stats ----
  {
    double ss = 0.0, sq = 0.0;
#pragma unroll
    for (int su = 0; su < 4; ++su) {
      const float bv = b3[su * 16 + col];
#pragma unroll
      for (int r = 0; r < 4; ++r) {
        const int j = jC + r;
        const float val = (j > 0) ? a3[su][r] + bv : 0.f;
        a3[su][r] = val;
        ss += (double)val;
        sq += (double)val * (double)val;
      }
    }
    blockStats(ss, sq, 64.0 * 128.0);
  }
  const float mean3 = bc[0], inv3 = bc[1];

  // ---- maxpool over j (norm'd), then 2-layer MLP ----
#pragma unroll
  for (int su = 0; su < 4; ++su) {
    float pm = -3.4e38f;
#pragma unroll
    for (int r = 0; r < 4; ++r) pm = fmaxf(pm, (a3[su][r] - mean3) * inv3);
    pm = fmaxf(pm, __shfl_xor(pm, 16, 64));
    pm = fmaxf(pm, __shfl_xor(pm, 32, 64));
    if (lane < 16) poolw[w][su * 16 + col] = pm;
  }
  __syncthreads();

  if (w == 0) {
    float hval = 0.f;
    if (lane < 32) {
      float a = fb1[lane];
#pragma unroll 8
      for (int c = 0; c < 64; ++c) {
        float p = poolw[0][c];
#pragma unroll
        for (int ww = 1; ww < 8; ++ww) p = fmaxf(p, poolw[ww][c]);
        a = fmaf(p, fw1[lane * 64 + c], a);
      }
      hval = fmaxf(a, 0.f) * fw2[lane];
    }
#pragma unroll
    for (int o = 32; o > 0; o >>= 1) hval += __shfl_down(hval, o, 64);
    if (lane == 0) out[b] = hval + fb2[0];
  }
}

// ---------------------------------------------------------------------------
extern "C" void kernel_launch(void* const* d_in, const int* in_sizes, int n_in,
                              void* d_out, int out_size, void* d_ws, size_t ws_size,
                              hipStream_t stream) {
  const float* feature   = (const float*)d_in[0];
  const void*  indexes   = d_in[1];
  const float* col_embed = (const float*)d_in[2];
  const float* op_embed  = (const float*)d_in[3];
  const float* w1  = (const float*)d_in[4];
  const float* b1  = (const float*)d_in[5];
  const float* w2  = (const float*)d_in[6];
  const float* b2  = (const float*)d_in[7];
  const float* w3  = (const float*)d_in[8];
  const float* b3  = (const float*)d_in[9];
  const float* fw1 = (const float*)d_in[10];
  const float* fb1 = (const float*)d_in[11];
  const float* fw2 = (const float*)d_in[12];
  const float* fb2 = (const float*)d_in[13];
  float* out = (float*)d_out;

  char* ws = (char*)d_ws;
  size_t off = 0;
  auto carve = [&](size_t bytes) -> char* {
    off = (off + 255) & ~(size_t)255;
    char* p = ws + off;
    off += bytes;
    return p;
  };
  int*   idx32    = (int*)carve((size_t)S_IDX * sizeof(int));
  short* w1h      = (short*)carve((size_t)S_P1 * sizeof(short));
  short* w1l      = (short*)carve((size_t)S_P1 * sizeof(short));
  short* w2h      = (short*)carve((size_t)S_P2 * sizeof(short));
  short* w2l      = (short*)carve((size_t)S_P2 * sizeof(short));
  short* w3h      = (short*)carve((size_t)S_P3 * sizeof(short));
  short* w3l      = (short*)carve((size_t)S_P3 * sizeof(short));
  short* collateH = (short*)carve((size_t)B_ * 128 * KPAD1 * sizeof(short));
  short* collateL = (short*)carve((size_t)B_ * 128 * KPAD1 * sizeof(short));
  (void)ws_size; (void)in_sizes; (void)n_in; (void)out_size;

  hipLaunchKernelGGL(prep_embed_kernel, dim3(EMBED_BLOCKS + PREP_BLOCKS), dim3(512), 0, stream,
                     feature, col_embed, op_embed, collateH, collateL,
                     indexes, idx32, w1, w1h, w1l, w2, w2h, w2l, w3, w3h, w3l);
  hipLaunchKernelGGL(fused_kernel, dim3(B_), dim3(512), 0, stream,
                     collateH, collateL, idx32,
                     w1h, w1l, w2h, w2l, w3h, w3l,
                     b1, b2, b3, fw1, fb1, fw2, fb2, out);
}

// Round 12
// 127.999 us; speedup vs baseline: 1.7416x; 1.7416x over previous
//
#include <hip/hip_runtime.h>
#include <hip/hip_bf16.h>
#include <math.h>

// Problem constants (B, N, D) = (256, 128, 128)
#define B_    256
#define N_    128
#define MAXP  30
#define OTHER_ 35
#define CIN1  131
#define NIDX  381

#define KPAD1 160
#define KPAD2 256
#define KPAD3 128
#define S_IDX (B_ * NIDX)          // 97536
#define S_P1  (15 * 8 * 2 * 512)   // 122880  (gks * NWO8 * SUB2 * 512)
#define S_P2  (24 * 4 * 2 * 512)   // 98304
#define S_P3  (12 * 4 * 1 * 512)   // 24576
#define PREP_TOTAL (S_IDX + S_P1 + S_P2 + S_P3)
#define PREP_BLOCKS ((PREP_TOTAL + 511) / 512)
#define EMBED_BLOCKS (B_ * 4)

typedef short short8 __attribute__((ext_vector_type(8)));
typedef float f32x4 __attribute__((ext_vector_type(4)));

// RNE split of f32 into hi/lo bf16 via bit math (prep only)
__device__ inline void split1(float v, short& h, short& l) {
  unsigned u = __float_as_uint(v);
  unsigned hb = (u + 0x7fffu + ((u >> 16) & 1u)) >> 16;
  float fh = __uint_as_float(hb << 16);
  float r = v - fh;
  unsigned u2 = __float_as_uint(r);
  unsigned lb = (u2 + 0x7fffu + ((u2 >> 16) & 1u)) >> 16;
  h = (short)hb;
  l = (short)lb;
}

// RNE split via HW cvt — hot path
__device__ inline void split2(float v, short& h, short& l) {
  __hip_bfloat16 hb = __float2bfloat16(v);
  float fh = __bfloat162float(hb);
  __hip_bfloat16 lb = __float2bfloat16(v - fh);
  __builtin_memcpy(&h, &hb, 2);
  __builtin_memcpy(&l, &lb, 2);
}

// ---------------------------------------------------------------------------
// Weight pack: l -> [gks][g][su][lane][e]; g in [0,NWO). Value w[oc][ch][kk],
// oc=(g*SUB+su)*16+(lane&15), ctot=gks*32+((lane>>4)&3)*8+e,
// kk=ctot/KPAD, ch=ctot%KPAD (0 if ch>=KREAL).
// ---------------------------------------------------------------------------
template <int KREAL, int KPAD, int SUB, int NWO>
__device__ inline void packw(int l, const float* __restrict__ w,
                             short* __restrict__ oh, short* __restrict__ ol) {
  const int e = l & 7;
  const int lane = (l >> 3) & 63;
  const int x = l >> 9;
  const int su = x % SUB;
  const int y = x / SUB;
  const int g = y % NWO;
  const int gks = y / NWO;
  const int oc = (g * SUB + su) * 16 + (lane & 15);
  const int ctot = gks * 32 + ((lane >> 4) & 3) * 8 + e;
  const int kk = ctot / KPAD;
  const int ch = ctot - kk * KPAD;
  const float v = (ch < KREAL) ? w[(oc * KREAL + ch) * 3 + kk] : 0.f;
  short h, lo;
  split1(v, h, lo);
  oh[l] = h;
  ol[l] = lo;
}

// ---------------------------------------------------------------------------
// Merged prep + embed (identical to r10).
// ---------------------------------------------------------------------------
__global__ __launch_bounds__(512) void prep_embed_kernel(
    const float* __restrict__ feature,
    const float* __restrict__ col_embed,   // (200,32)
    const float* __restrict__ op_embed,    // (20,32)
    short* __restrict__ collateH, short* __restrict__ collateL,
    const void* __restrict__ rawIdx, int* __restrict__ idx32,
    const float* __restrict__ w1, short* __restrict__ w1h, short* __restrict__ w1l,
    const float* __restrict__ w2, short* __restrict__ w2h, short* __restrict__ w2l,
    const float* __restrict__ w3, short* __restrict__ w3h, short* __restrict__ w3l) {
  const int bx = blockIdx.x;
  const int tid = threadIdx.x;

  if (bx >= EMBED_BLOCKS) {
    const int gid = (bx - EMBED_BLOCKS) * 512 + tid;
    if (gid < S_IDX) {
      // int64 LE view is (v,0,v,0,...) with v in [0,128)
      const int* r32 = (const int*)rawIdx;
      const int lane = tid & 63;
      const int lo = r32[2 * lane];
      const int hi = r32[2 * lane + 1];
      const bool ok = (hi == 0 && lo >= 0 && lo < N_);
      const bool is64 = __all(ok);
      idx32[gid] = is64 ? (int)((const long long*)rawIdx)[gid] : ((const int*)rawIdx)[gid];
    } else if (gid < S_IDX + S_P1) {
      packw<131, KPAD1, 2, 8>(gid - S_IDX, w1, w1h, w1l);
    } else if (gid < S_IDX + S_P1 + S_P2) {
      packw<256, KPAD2, 2, 4>(gid - (S_IDX + S_P1), w2, w2h, w2l);
    } else if (gid < PREP_TOTAL) {
      packw<128, KPAD3, 1, 4>(gid - (S_IDX + S_P1 + S_P2), w3, w3h, w3l);
    }
    return;
  }

  __shared__ float feat[128 * 33];
  __shared__ float ce[200 * 32];
  __shared__ float oe[20 * 32];
  const int b = bx >> 2;
  const int n0 = (bx & 3) * 32;
  const float* fb = feature + (size_t)b * 16384;

  {
    const float4* s = (const float4*)col_embed;
    float4* d = (float4*)ce;
#pragma unroll
    for (int it = 0; it < 4; ++it) {
      const int t = it * 512 + tid;
      if (t < 1600) d[t] = s[t];
    }
    if (tid < 160) ((float4*)oe)[tid] = ((const float4*)op_embed)[tid];
  }
  {
    const int d = tid >> 2;
    const int c8 = (tid & 3) * 8;
    const float4 v0 = *reinterpret_cast<const float4*>(&fb[d * 128 + n0 + c8]);
    const float4 v1 = *reinterpret_cast<const float4*>(&fb[d * 128 + n0 + c8 + 4]);
    float* p = &feat[d * 33 + c8];
    p[0] = v0.x; p[1] = v0.y; p[2] = v0.z; p[3] = v0.w;
    p[4] = v1.x; p[5] = v1.y; p[6] = v1.z; p[7] = v1.w;
  }
  __syncthreads();

  const int wv = tid >> 6;
  const int lane = tid & 63;
  const int cl = lane & 31;

#pragma unroll
  for (int ni = 0; ni < 4; ++ni) {
    const int nl = wv * 4 + ni;
    const int n = n0 + nl;
    int civ = 0, oiv = 0;
    if (lane < MAXP) civ = (int)feat[(OTHER_ + lane) * 33 + nl];
    if (lane >= 32 && lane < 32 + MAXP) oiv = (int)feat[(OTHER_ + MAXP + (lane - 32)) * 33 + nl];
    const int L = (int)feat[95 * 33 + nl];

    float acc = 0.f;
    for (int i = 0; i < L; ++i) {
      const int cv = __shfl(civ, i);
      const int ov = __shfl(oiv, 32 + i);
      acc += (lane < 32) ? ce[cv * 32 + cl] : oe[ov * 32 + cl];
    }

    short* outH = collateH + ((size_t)b * 128 + n) * KPAD1;
    short* outL = collateL + ((size_t)b * 128 + n) * KPAD1;
    short h, l;
    split2(acc, h, l);
    outH[35 + lane] = h; outL[35 + lane] = l;
    if (lane < 35) {
      split2(feat[lane * 33 + nl], h, l);
      outH[lane] = h; outL[lane] = l;
    }
    if (lane < 32) {
      split2(feat[(96 + lane) * 33 + nl], h, l);
      outH[99 + lane] = h; outL[99 + lane] = l;
    }
    if (lane < 29) { outH[131 + lane] = 0; outL[131 + lane] = 0; }
  }
}

// ---------------------------------------------------------------------------
// MFMA tree conv v6: r10 structure + DOUBLE-BUFFERED operand streams.
// Block = (batch, j-half, oc-chunk); 8 waves = (wj 0..1)x(wo 0..3);
// wave = 32 j (JT=2) x SUB*16 oc (weight group g = co*4+wo).
// Per k-iteration: issue it+1's weight VMEM loads + A LDS reads into the
// alternate register set, then run it's 3*2*SUB MFMAs — latency hides under
// compute. All indices compile-time after unroll (parity folds; no scratch).
// X staged in 64-ch stages (CINP 72, ~37 KB LDS) with reg prefetch.
// ---------------------------------------------------------------------------
template <int KPAD, int SUB, int NWO, int OCCH, bool PURE, bool NORM_IN,
          int NCHIN, int NSTG>
__global__ __launch_bounds__(512, 4) void convm_kernel(
    const float* __restrict__ X,        // (B,128,KPAD) f32 (SPLIT mode)
    const short* __restrict__ XH,       // (B,128,KPAD) bf16-hi (PURE mode)
    const short* __restrict__ XL,       // (B,128,KPAD) bf16-lo (PURE mode)
    const int* __restrict__ idx,        // (B,381)
    const short* __restrict__ wH, const short* __restrict__ wL,
    const float* __restrict__ bias,     // (COUT)
    const double* __restrict__ statsIn, // (B,NCHIN,2) or null
    float* __restrict__ Y,              // (B,128,COUT)
    double* __restrict__ statsOut) {    // (B,2*OCCH,2) partials
  constexpr int KPS = KPAD / 32;
  constexpr int COUT = NWO * SUB * 16 * OCCH / OCCH;  // = NWO*SUB*16 per full
  constexpr int COUTT = NWO * SUB * 16;               // total columns in Y
  constexpr int CINP = 72;
  constexpr int MAXIT = 2;

  __shared__ short xhi[128 * CINP];
  __shared__ short xlo[128 * CINP];
  __shared__ int nb_s[NIDX];
  __shared__ double red[16];

  const int b = blockIdx.x;
  const int cj = blockIdx.y;
  const int co = blockIdx.z;
  const int jbase = cj * 64;
  const int tid = threadIdx.x;
  const int lane = tid & 63;
  const int w = tid >> 6;
  const int wj = w >> 2;
  const int g = co * 4 + (w & 3);
  const int grp = (lane >> 4) & 3;

  float mean = 0.f, inv = 1.f;
  if (NORM_IN) {
    double S = 0.0, Q = 0.0;
#pragma unroll
    for (int i = 0; i < NCHIN; ++i) {
      S += statsIn[(b * NCHIN + i) * 2];
      Q += statsIn[(b * NCHIN + i) * 2 + 1];
    }
    const double cnt = (double)KPAD * 128.0;
    const double m = S / cnt;
    double var = (Q - S * S / cnt) / (cnt - 1.0);
    if (var < 0.0) var = 0.0;
    mean = (float)m;
    inv = (float)(1.0 / (sqrt(var) + 1e-5));
  }

  const float* __restrict__ Xb = X + (size_t)b * (128 * KPAD);
  const short* __restrict__ XHb = XH + (size_t)b * (128 * KPAD);
  const short* __restrict__ XLb = XL + (size_t)b * (128 * KPAD);
  const short8* __restrict__ wH8 = (const short8*)wH;
  const short8* __restrict__ wL8 = (const short8*)wL;

  // X staging prefetch regs
  short8 rh[MAXIT], rl[MAXIT];
  float4 f0[MAXIT], f1[MAXIT];

  auto LOADS = [&](int s) {
    const int chb = s * 64;
    const int chn = (KPAD - chb < 64) ? (KPAD - chb) : 64;
    const int PKs = chn / 8;
#pragma unroll
    for (int it = 0; it < MAXIT; ++it) {
      const int t = it * 512 + tid;
      if (t < 128 * PKs) {
        const int n = t / PKs;
        const int ch0 = chb + (t - n * PKs) * 8;
        if constexpr (PURE) {
          rh[it] = *reinterpret_cast<const short8*>(&XHb[n * KPAD + ch0]);
          rl[it] = *reinterpret_cast<const short8*>(&XLb[n * KPAD + ch0]);
        } else {
          f0[it] = *reinterpret_cast<const float4*>(&Xb[n * KPAD + ch0]);
          f1[it] = *reinterpret_cast<const float4*>(&Xb[n * KPAD + ch0 + 4]);
        }
      }
    }
  };
  auto WRITES = [&](int s) {
    const int chb = s * 64;
    const int chn = (KPAD - chb < 64) ? (KPAD - chb) : 64;
    const int PKs = chn / 8;
#pragma unroll
    for (int it = 0; it < MAXIT; ++it) {
      const int t = it * 512 + tid;
      if (t < 128 * PKs) {
        const int n = t / PKs;
        const int c0 = (t - n * PKs) * 8;
        short8 h8, l8;
        if constexpr (PURE) {
          h8 = rh[it];
          l8 = rl[it];
        } else {
          const float vv[8] = {f0[it].x, f0[it].y, f0[it].z, f0[it].w,
                               f1[it].x, f1[it].y, f1[it].z, f1[it].w};
#pragma unroll
          for (int i = 0; i < 8; ++i) {
            float v = vv[i];
            if (NORM_IN) {
              v = (v - mean) * inv;
              v = fmaxf(v, 0.01f * v);
            }
            short h, l;
            split2(v, h, l);
            h8[i] = h;
            l8[i] = l;
          }
        }
        const int ei = n * CINP + c0;
        *reinterpret_cast<short8*>(&xhi[ei]) = h8;
        *reinterpret_cast<short8*>(&xlo[ei]) = l8;
      }
    }
  };

  int nbr[2][3];
  f32x4 acc[2][SUB];
#pragma unroll
  for (int jt = 0; jt < 2; ++jt)
#pragma unroll
    for (int su = 0; su < SUB; ++su) {
      acc[jt][su][0] = 0.f; acc[jt][su][1] = 0.f;
      acc[jt][su][2] = 0.f; acc[jt][su][3] = 0.f;
    }

  // double-buffered operand registers
  short8 pah[2][2], pal[2][2];          // [parity][jt]
  short8 pwh[2][SUB], pwl[2][SUB];      // [parity][su]

  auto LOADW = [&](int gks, int p) {
#pragma unroll
    for (int su = 0; su < SUB; ++su) {
      const int wi = ((gks * NWO + g) * SUB + su) * 64 + lane;
      pwh[p][su] = wH8[wi];
      pwl[p][su] = wL8[wi];
    }
  };
  auto LOADA = [&](int kk, int choff, int p) {
#pragma unroll
    for (int jt = 0; jt < 2; ++jt) {
      const int ei = nbr[jt][kk] * CINP + choff;
      pah[p][jt] = *reinterpret_cast<const short8*>(&xhi[ei]);
      pal[p][jt] = *reinterpret_cast<const short8*>(&xlo[ei]);
    }
  };
  auto DOMFMA = [&](int p) {
#pragma unroll
    for (int jt = 0; jt < 2; ++jt)
#pragma unroll
      for (int su = 0; su < SUB; ++su) {
        acc[jt][su] = __builtin_amdgcn_mfma_f32_16x16x32_bf16(pah[p][jt], pwh[p][su], acc[jt][su], 0, 0, 0);
        acc[jt][su] = __builtin_amdgcn_mfma_f32_16x16x32_bf16(pal[p][jt], pwh[p][su], acc[jt][su], 0, 0, 0);
        acc[jt][su] = __builtin_amdgcn_mfma_f32_16x16x32_bf16(pah[p][jt], pwl[p][su], acc[jt][su], 0, 0, 0);
      }
  };

  LOADS(0);
  if (tid < NIDX) nb_s[tid] = idx[b * NIDX + tid];
  WRITES(0);
  __syncthreads();

#pragma unroll
  for (int jt = 0; jt < 2; ++jt) {
    const int j = jbase + wj * 32 + jt * 16 + (lane & 15);
#pragma unroll
    for (int kk = 0; kk < 3; ++kk)
      nbr[jt][kk] = (j > 0) ? nb_s[(j - 1) * 3 + kk] : 0;
  }

#pragma unroll
  for (int s = 0; s < NSTG; ++s) {
    if (s + 1 < NSTG) LOADS(s + 1);   // X for next stage, in flight

    const int chb = s * 64;
    const int chn = (KPAD - chb < 64) ? (KPAD - chb) : 64;
    const int nks = chn / 32;          // 2 or 1 (constant-folds per s)
    const int ks0 = s * 2;
    const int NIT = 3 * nks;

    // k-loop with 1-deep double buffering of W (VMEM) and A (LDS)
    LOADW(0 * KPS + ks0 + 0, 0);
    LOADA(0, grp * 8, 0);
#pragma unroll
    for (int it = 0; it < NIT; ++it) {
      if (it + 1 < NIT) {
        const int kk2 = (it + 1) / nks;
        const int q2 = (it + 1) - kk2 * nks;
        LOADW(kk2 * KPS + ks0 + q2, (it + 1) & 1);
        LOADA(kk2, q2 * 32 + grp * 8, (it + 1) & 1);
      }
      DOMFMA(it & 1);
    }

    if (s + 1 < NSTG) {
      __syncthreads();     // readers done with stage s
      WRITES(s + 1);
      __syncthreads();     // stage s+1 visible
    }
  }

  // ---- epilogue: bias, zero col, store, f64 stats ----
  double s_sum = 0.0, s_sq = 0.0;
#pragma unroll
  for (int su = 0; su < SUB; ++su) {
    const int oc = (g * SUB + su) * 16 + (lane & 15);
    const float bv = bias[oc];
#pragma unroll
    for (int jt = 0; jt < 2; ++jt) {
#pragma unroll
      for (int r = 0; r < 4; ++r) {
        const int j = jbase + wj * 32 + jt * 16 + grp * 4 + r;
        const float val = (j > 0) ? acc[jt][su][r] + bv : 0.f;
        Y[((size_t)b * 128 + j) * COUTT + oc] = val;
        s_sum += (double)val;
        s_sq += (double)val * (double)val;
      }
    }
  }

#pragma unroll
  for (int o = 32; o > 0; o >>= 1) {
    s_sum += __shfl_down(s_sum, o, 64);
    s_sq  += __shfl_down(s_sq, o, 64);
  }
  if (lane == 0) { red[w * 2] = s_sum; red[w * 2 + 1] = s_sq; }
  __syncthreads();
  if (tid == 0) {
    double S = 0.0, Q = 0.0;
#pragma unroll
    for (int i = 0; i < 8; ++i) { S += red[i * 2]; Q += red[i * 2 + 1]; }
    const int chunk = cj * OCCH + co;
    statsOut[(b * (2 * OCCH) + chunk) * 2] = S;
    statsOut[(b * (2 * OCCH) + chunk) * 2 + 1] = Q;
  }
}

// ---------------------------------------------------------------------------
// Final: combine conv3 stats partials (2), normalize, maxpool, 2-layer MLP.
// ---------------------------------------------------------------------------
__global__ __launch_bounds__(64) void final_kernel(
    const float* __restrict__ Y3,      // (B,128,64)
    const double* __restrict__ st,     // (B,2,2)
    const float* __restrict__ fw1,     // (32,64)
    const float* __restrict__ fb1,     // (32)
    const float* __restrict__ fw2,     // (1,32)
    const float* __restrict__ fb2,     // (1)
    float* __restrict__ out) {
  const int b = blockIdx.x;
  const int lane = threadIdx.x;

  const double S = st[(b * 2) * 2] + st[(b * 2 + 1) * 2];
  const double Q = st[(b * 2) * 2 + 1] + st[(b * 2 + 1) * 2 + 1];
  const double cnt = 64.0 * 128.0;
  const double m = S / cnt;
  double var = (Q - S * S / cnt) / (cnt - 1.0);
  if (var < 0.0) var = 0.0;
  const float mean = (float)m;
  const float inv = (float)(1.0 / (sqrt(var) + 1e-5));

  const float* Yb = Y3 + (size_t)b * 128 * 64;
  float mx = -3.4e38f;
  for (int n = 0; n < 128; ++n) {
    const float v = (Yb[n * 64 + lane] - mean) * inv;
    mx = fmaxf(mx, v);
  }
  __shared__ float pooled[64];
  __shared__ float hs[32];
  pooled[lane] = mx;
  __syncthreads();
  if (lane < 32) {
    float a = fb1[lane];
    for (int c = 0; c < 64; ++c) a = fmaf(pooled[c], fw1[lane * 64 + c], a);
    hs[lane] = fmaxf(a, 0.f);
  }
  __syncthreads();
  if (lane == 0) {
    float s = fb2[0];
    for (int t = 0; t < 32; ++t) s = fmaf(hs[t], fw2[t], s);
    out[b] = s;
  }
}

// ---------------------------------------------------------------------------
extern "C" void kernel_launch(void* const* d_in, const int* in_sizes, int n_in,
                              void* d_out, int out_size, void* d_ws, size_t ws_size,
                              hipStream_t stream) {
  const float* feature   = (const float*)d_in[0];
  const void*  indexes   = d_in[1];
  const float* col_embed = (const float*)d_in[2];
  const float* op_embed  = (const float*)d_in[3];
  const float* w1  = (const float*)d_in[4];
  const float* b1  = (const float*)d_in[5];
  const float* w2  = (const float*)d_in[6];
  const float* b2  = (const float*)d_in[7];
  const float* w3  = (const float*)d_in[8];
  const float* b3  = (const float*)d_in[9];
  const float* fw1 = (const float*)d_in[10];
  const float* fb1 = (const float*)d_in[11];
  const float* fw2 = (const float*)d_in[12];
  const float* fb2 = (const float*)d_in[13];
  float* out = (float*)d_out;

  char* ws = (char*)d_ws;
  size_t off = 0;
  auto carve = [&](size_t bytes) -> char* {
    off = (off + 255) & ~(size_t)255;
    char* p = ws + off;
    off += bytes;
    return p;
  };
  int*    idx32    = (int*)carve((size_t)S_IDX * sizeof(int));
  short*  w1h      = (short*)carve((size_t)S_P1 * sizeof(short));
  short*  w1l      = (short*)carve((size_t)S_P1 * sizeof(short));
  short*  w2h      = (short*)carve((size_t)S_P2 * sizeof(short));
  short*  w2l      = (short*)carve((size_t)S_P2 * sizeof(short));
  short*  w3h      = (short*)carve((size_t)S_P3 * sizeof(short));
  short*  w3l      = (short*)carve((size_t)S_P3 * sizeof(short));
  short*  collateH = (short*)carve((size_t)B_ * 128 * KPAD1 * sizeof(short));
  short*  collateL = (short*)carve((size_t)B_ * 128 * KPAD1 * sizeof(short));
  float*  Y1       = (float*)carve((size_t)B_ * 128 * 256 * sizeof(float));
  float*  Y2       = (float*)carve((size_t)B_ * 128 * 128 * sizeof(float));
  float*  Y3       = (float*)carve((size_t)B_ * 128 * 64 * sizeof(float));
  double* st1      = (double*)carve((size_t)B_ * 4 * 2 * sizeof(double));
  double* st2      = (double*)carve((size_t)B_ * 2 * 2 * sizeof(double));
  double* st3      = (double*)carve((size_t)B_ * 2 * 2 * sizeof(double));
  (void)ws_size; (void)in_sizes; (void)n_in; (void)out_size;

  hipLaunchKernelGGL(prep_embed_kernel, dim3(EMBED_BLOCKS + PREP_BLOCKS), dim3(512), 0, stream,
                     feature, col_embed, op_embed, collateH, collateL,
                     indexes, idx32, w1, w1h, w1l, w2, w2h, w2l, w3, w3h, w3l);
  // conv1: PURE, K=160 (3 stages 64/64/32), COUT 256 in 2 oc-chunks, NWO 8
  hipLaunchKernelGGL((convm_kernel<KPAD1, 2, 8, 2, true, false, 1, 3>),
                     dim3(B_, 2, 2), dim3(512), 0, stream,
                     (const float*)nullptr, collateH, collateL, idx32,
                     w1h, w1l, b1, (const double*)nullptr, Y1, st1);
  // conv2: SPLIT, K=256 (4 stages of 64), COUT 128, NWO 4, NCHIN 4
  hipLaunchKernelGGL((convm_kernel<KPAD2, 2, 4, 1, false, true, 4, 4>),
                     dim3(B_, 2, 1), dim3(512), 0, stream,
                     Y1, (const short*)nullptr, (const short*)nullptr, idx32,
                     w2h, w2l, b2, st1, Y2, st2);
  // conv3: SPLIT, K=128 (2 stages of 64), COUT 64, SUB 1, NWO 4, NCHIN 2
  hipLaunchKernelGGL((convm_kernel<KPAD3, 1, 4, 1, false, true, 2, 2>),
                     dim3(B_, 2, 1), dim3(512), 0, stream,
                     Y2, (const short*)nullptr, (const short*)nullptr, idx32,
                     w3h, w3l, b3, st2, Y3, st3);
  hipLaunchKernelGGL(final_kernel, dim3(B_), dim3(64), 0, stream,
                     Y3, st3, fw1, fb1, fw2, fb2, out);
}

// Round 13
// 86.061 us; speedup vs baseline: 2.5902x; 1.4873x over previous
//
#include <hip/hip_runtime.h>
#include <hip/hip_bf16.h>
#include <math.h>

// Problem constants (B, N, D) = (256, 128, 128)
#define B_    256
#define N_    128
#define MAXP  30
#define OTHER_ 35
#define CIN1  131
#define NIDX  381

#define KPAD1 160
#define KPAD2 256
#define KPAD3 128
#define S_IDX (B_ * NIDX)          // 97536
#define S_P1  (15 * 2 * 8 * 512)   // 122880  (gks * NWO2 * SUB8 * 512)
#define S_P2  (24 * 2 * 4 * 512)   // 98304
#define S_P3  (12 * 2 * 2 * 512)   // 24576
#define PREP_TOTAL (S_IDX + S_P1 + S_P2 + S_P3)
#define PREP_BLOCKS ((PREP_TOTAL + 511) / 512)
#define EMBED_BLOCKS (B_ * 4)

typedef short short8 __attribute__((ext_vector_type(8)));
typedef float f32x4 __attribute__((ext_vector_type(4)));

// RNE split of f32 into hi/lo bf16 via bit math (prep only)
__device__ inline void split1(float v, short& h, short& l) {
  unsigned u = __float_as_uint(v);
  unsigned hb = (u + 0x7fffu + ((u >> 16) & 1u)) >> 16;
  float fh = __uint_as_float(hb << 16);
  float r = v - fh;
  unsigned u2 = __float_as_uint(r);
  unsigned lb = (u2 + 0x7fffu + ((u2 >> 16) & 1u)) >> 16;
  h = (short)hb;
  l = (short)lb;
}

// RNE split via HW cvt — hot path
__device__ inline void split2(float v, short& h, short& l) {
  __hip_bfloat16 hb = __float2bfloat16(v);
  float fh = __bfloat162float(hb);
  __hip_bfloat16 lb = __float2bfloat16(v - fh);
  __builtin_memcpy(&h, &hb, 2);
  __builtin_memcpy(&l, &lb, 2);
}

// ---------------------------------------------------------------------------
// Weight pack: l -> [gks][g][su][lane][e]; g in [0,NWO). Value w[oc][ch][kk],
// oc=(g*SUB+su)*16+(lane&15), ctot=gks*32+((lane>>4)&3)*8+e,
// kk=ctot/KPAD, ch=ctot%KPAD (0 if ch>=KREAL).
// ---------------------------------------------------------------------------
template <int KREAL, int KPAD, int SUB, int NWO>
__device__ inline void packw(int l, const float* __restrict__ w,
                             short* __restrict__ oh, short* __restrict__ ol) {
  const int e = l & 7;
  const int lane = (l >> 3) & 63;
  const int x = l >> 9;
  const int su = x % SUB;
  const int y = x / SUB;
  const int g = y % NWO;
  const int gks = y / NWO;
  const int oc = (g * SUB + su) * 16 + (lane & 15);
  const int ctot = gks * 32 + ((lane >> 4) & 3) * 8 + e;
  const int kk = ctot / KPAD;
  const int ch = ctot - kk * KPAD;
  const float v = (ch < KREAL) ? w[(oc * KREAL + ch) * 3 + kk] : 0.f;
  short h, lo;
  split1(v, h, lo);
  oh[l] = h;
  ol[l] = lo;
}

// ---------------------------------------------------------------------------
// Merged prep + embed (as r10/r12; new pack factorizations NWO=2).
// ---------------------------------------------------------------------------
__global__ __launch_bounds__(512) void prep_embed_kernel(
    const float* __restrict__ feature,
    const float* __restrict__ col_embed,   // (200,32)
    const float* __restrict__ op_embed,    // (20,32)
    short* __restrict__ collateH, short* __restrict__ collateL,
    const void* __restrict__ rawIdx, int* __restrict__ idx32,
    const float* __restrict__ w1, short* __restrict__ w1h, short* __restrict__ w1l,
    const float* __restrict__ w2, short* __restrict__ w2h, short* __restrict__ w2l,
    const float* __restrict__ w3, short* __restrict__ w3h, short* __restrict__ w3l) {
  const int bx = blockIdx.x;
  const int tid = threadIdx.x;

  if (bx >= EMBED_BLOCKS) {
    const int gid = (bx - EMBED_BLOCKS) * 512 + tid;
    if (gid < S_IDX) {
      // int64 LE view is (v,0,v,0,...) with v in [0,128)
      const int* r32 = (const int*)rawIdx;
      const int lane = tid & 63;
      const int lo = r32[2 * lane];
      const int hi = r32[2 * lane + 1];
      const bool ok = (hi == 0 && lo >= 0 && lo < N_);
      const bool is64 = __all(ok);
      idx32[gid] = is64 ? (int)((const long long*)rawIdx)[gid] : ((const int*)rawIdx)[gid];
    } else if (gid < S_IDX + S_P1) {
      packw<131, KPAD1, 8, 2>(gid - S_IDX, w1, w1h, w1l);
    } else if (gid < S_IDX + S_P1 + S_P2) {
      packw<256, KPAD2, 4, 2>(gid - (S_IDX + S_P1), w2, w2h, w2l);
    } else if (gid < PREP_TOTAL) {
      packw<128, KPAD3, 2, 2>(gid - (S_IDX + S_P1 + S_P2), w3, w3h, w3l);
    }
    return;
  }

  __shared__ float feat[128 * 33];
  __shared__ float ce[200 * 32];
  __shared__ float oe[20 * 32];
  const int b = bx >> 2;
  const int n0 = (bx & 3) * 32;
  const float* fb = feature + (size_t)b * 16384;

  {
    const float4* s = (const float4*)col_embed;
    float4* d = (float4*)ce;
#pragma unroll
    for (int it = 0; it < 4; ++it) {
      const int t = it * 512 + tid;
      if (t < 1600) d[t] = s[t];
    }
    if (tid < 160) ((float4*)oe)[tid] = ((const float4*)op_embed)[tid];
  }
  {
    const int d = tid >> 2;
    const int c8 = (tid & 3) * 8;
    const float4 v0 = *reinterpret_cast<const float4*>(&fb[d * 128 + n0 + c8]);
    const float4 v1 = *reinterpret_cast<const float4*>(&fb[d * 128 + n0 + c8 + 4]);
    float* p = &feat[d * 33 + c8];
    p[0] = v0.x; p[1] = v0.y; p[2] = v0.z; p[3] = v0.w;
    p[4] = v1.x; p[5] = v1.y; p[6] = v1.z; p[7] = v1.w;
  }
  __syncthreads();

  const int wv = tid >> 6;
  const int lane = tid & 63;
  const int cl = lane & 31;

#pragma unroll
  for (int ni = 0; ni < 4; ++ni) {
    const int nl = wv * 4 + ni;
    const int n = n0 + nl;
    int civ = 0, oiv = 0;
    if (lane < MAXP) civ = (int)feat[(OTHER_ + lane) * 33 + nl];
    if (lane >= 32 && lane < 32 + MAXP) oiv = (int)feat[(OTHER_ + MAXP + (lane - 32)) * 33 + nl];
    const int L = (int)feat[95 * 33 + nl];

    float acc = 0.f;
    for (int i = 0; i < L; ++i) {
      const int cv = __shfl(civ, i);
      const int ov = __shfl(oiv, 32 + i);
      acc += (lane < 32) ? ce[cv * 32 + cl] : oe[ov * 32 + cl];
    }

    short* outH = collateH + ((size_t)b * 128 + n) * KPAD1;
    short* outL = collateL + ((size_t)b * 128 + n) * KPAD1;
    short h, l;
    split2(acc, h, l);
    outH[35 + lane] = h; outL[35 + lane] = l;
    if (lane < 35) {
      split2(feat[lane * 33 + nl], h, l);
      outH[lane] = h; outL[lane] = l;
    }
    if (lane < 32) {
      split2(feat[(96 + lane) * 33 + nl], h, l);
      outH[99 + lane] = h; outL[99 + lane] = l;
    }
    if (lane < 29) { outH[131 + lane] = 0; outL[131 + lane] = 0; }
  }
}

// ---------------------------------------------------------------------------
// FUSED conv1+norm+conv2+norm+conv3+norm+maxpool+MLP, v2.
// Block = one batch (grid 256, 1/CU, 2 waves/SIMD -> VGPR up to 256).
// 8 waves = (wj 0..3) x (wo 0..1): wave owns j in [wj*32,+32) (JT=2) and an
// oc-HALF (SUB tiles of 16). Per gks the block reads each weight fragment
// once per wo (4x wj-reuse served by L1) — no r11-style 8x redundancy.
// Inter-layer: outputs live in registers; staging to LDS (norm+leaky+split)
// written by the owning wo-waves. Only global write: out[b].
// ---------------------------------------------------------------------------
__global__ __launch_bounds__(512, 1) void fused_kernel(
    const short* __restrict__ XH, const short* __restrict__ XL,
    const int* __restrict__ idx,
    const short* __restrict__ w1h, const short* __restrict__ w1l,
    const short* __restrict__ w2h, const short* __restrict__ w2l,
    const short* __restrict__ w3h, const short* __restrict__ w3l,
    const float* __restrict__ b1, const float* __restrict__ b2,
    const float* __restrict__ b3,
    const float* __restrict__ fw1, const float* __restrict__ fb1,
    const float* __restrict__ fw2, const float* __restrict__ fb2,
    float* __restrict__ out) {
  constexpr int CINP = 72;

  __shared__ short sH[128 * CINP];
  __shared__ short sL[128 * CINP];
  __shared__ int nb_s[NIDX];
  __shared__ double red[16];
  __shared__ float bc[2];
  __shared__ float poolw[8][32];

  const int b = blockIdx.x;
  const int tid = threadIdx.x;
  const int lane = tid & 63;
  const int w = tid >> 6;
  const int wj = w >> 1;        // 0..3
  const int wo = w & 1;         // 0..1
  const int col = lane & 15;
  const int grp = (lane >> 4) & 3;
  const int jbase = wj * 32;

  const short8* __restrict__ wp1h = (const short8*)w1h;
  const short8* __restrict__ wp1l = (const short8*)w1l;
  const short8* __restrict__ wp2h = (const short8*)w2h;
  const short8* __restrict__ wp2l = (const short8*)w2l;
  const short8* __restrict__ wp3h = (const short8*)w3h;
  const short8* __restrict__ wp3l = (const short8*)w3l;

  const short* __restrict__ XHb = XH + (size_t)b * (128 * KPAD1);
  const short* __restrict__ XLb = XL + (size_t)b * (128 * KPAD1);
  short8 rh[2], rl[2];

  auto LOADS1 = [&](int s) {
    const int chb = s * 64;
    const int chn = (KPAD1 - chb < 64) ? (KPAD1 - chb) : 64;
    const int PKs = chn / 8;
#pragma unroll
    for (int it = 0; it < 2; ++it) {
      const int t = it * 512 + tid;
      if (t < 128 * PKs) {
        const int n = t / PKs;
        const int ch0 = chb + (t - n * PKs) * 8;
        rh[it] = *reinterpret_cast<const short8*>(&XHb[n * KPAD1 + ch0]);
        rl[it] = *reinterpret_cast<const short8*>(&XLb[n * KPAD1 + ch0]);
      }
    }
  };
  auto WRITES1 = [&](int s) {
    const int chb = s * 64;
    const int chn = (KPAD1 - chb < 64) ? (KPAD1 - chb) : 64;
    const int PKs = chn / 8;
#pragma unroll
    for (int it = 0; it < 2; ++it) {
      const int t = it * 512 + tid;
      if (t < 128 * PKs) {
        const int n = t / PKs;
        const int c0 = (t - n * PKs) * 8;
        *reinterpret_cast<short8*>(&sH[n * CINP + c0]) = rh[it];
        *reinterpret_cast<short8*>(&sL[n * CINP + c0]) = rl[it];
      }
    }
  };

  auto blockStats = [&](double ss, double sq, double cnt) {
#pragma unroll
    for (int o = 32; o > 0; o >>= 1) {
      ss += __shfl_down(ss, o, 64);
      sq += __shfl_down(sq, o, 64);
    }
    if (lane == 0) { red[w * 2] = ss; red[w * 2 + 1] = sq; }
    __syncthreads();
    if (tid == 0) {
      double S = 0.0, Q = 0.0;
#pragma unroll
      for (int i = 0; i < 8; ++i) { S += red[i * 2]; Q += red[i * 2 + 1]; }
      const double m = S / cnt;
      double var = (Q - S * S / cnt) / (cnt - 1.0);
      if (var < 0.0) var = 0.0;
      bc[0] = (float)m;
      bc[1] = (float)(1.0 / (sqrt(var) + 1e-5));
    }
    __syncthreads();
  };

  // ---------------- conv1: COUT 256, wave oc-half (SUB=8), JT=2 ----------
  f32x4 a1[2][8];
#pragma unroll
  for (int jt = 0; jt < 2; ++jt)
#pragma unroll
    for (int su = 0; su < 8; ++su) {
      a1[jt][su][0] = 0.f; a1[jt][su][1] = 0.f;
      a1[jt][su][2] = 0.f; a1[jt][su][3] = 0.f;
    }

  LOADS1(0);
  if (tid < NIDX) nb_s[tid] = idx[b * NIDX + tid];
  WRITES1(0);
  __syncthreads();

  int nbr[2][3];
#pragma unroll
  for (int jt = 0; jt < 2; ++jt) {
    const int jA = jbase + jt * 16 + col;
#pragma unroll
    for (int kk = 0; kk < 3; ++kk)
      nbr[jt][kk] = (jA > 0) ? nb_s[(jA - 1) * 3 + kk] : 0;
  }

#pragma unroll
  for (int s = 0; s < 3; ++s) {
    if (s < 2) LOADS1(s + 1);
    const int nks = (s == 2) ? 1 : 2;
#pragma unroll
    for (int kk = 0; kk < 3; ++kk) {
      for (int q = 0; q < nks; ++q) {
        const int gks = kk * 5 + s * 2 + q;
        short8 ah[2], al[2];
#pragma unroll
        for (int jt = 0; jt < 2; ++jt) {
          const int ei = nbr[jt][kk] * CINP + q * 32 + grp * 8;
          ah[jt] = *reinterpret_cast<const short8*>(&sH[ei]);
          al[jt] = *reinterpret_cast<const short8*>(&sL[ei]);
        }
        short8 bh[8], bl[8];
#pragma unroll
        for (int su = 0; su < 8; ++su) {
          const int wi = ((gks * 2 + wo) * 8 + su) * 64 + lane;
          bh[su] = wp1h[wi];
          bl[su] = wp1l[wi];
        }
#pragma unroll
        for (int jt = 0; jt < 2; ++jt)
#pragma unroll
          for (int su = 0; su < 8; ++su) {
            a1[jt][su] = __builtin_amdgcn_mfma_f32_16x16x32_bf16(ah[jt], bh[su], a1[jt][su], 0, 0, 0);
            a1[jt][su] = __builtin_amdgcn_mfma_f32_16x16x32_bf16(al[jt], bh[su], a1[jt][su], 0, 0, 0);
            a1[jt][su] = __builtin_amdgcn_mfma_f32_16x16x32_bf16(ah[jt], bl[su], a1[jt][su], 0, 0, 0);
          }
      }
    }
    if (s < 2) {
      __syncthreads();
      WRITES1(s + 1);
      __syncthreads();
    }
  }

  // ---- epilogue1: bias, zero col j=0, stats ----
  {
    double ss = 0.0, sq = 0.0;
#pragma unroll
    for (int su = 0; su < 8; ++su) {
      const float bv = b1[(wo * 8 + su) * 16 + col];
#pragma unroll
      for (int jt = 0; jt < 2; ++jt)
#pragma unroll
        for (int r = 0; r < 4; ++r) {
          const int j = jbase + jt * 16 + grp * 4 + r;
          const float val = (j > 0) ? a1[jt][su][r] + bv : 0.f;
          a1[jt][su][r] = val;
          ss += (double)val;
          sq += (double)val * (double)val;
        }
    }
    blockStats(ss, sq, 256.0 * 128.0);
  }
  const float mean1 = bc[0], inv1 = bc[1];

  // ---------------- conv2: COUT 128, SUB=4 ----------------
  f32x4 a2[2][4];
#pragma unroll
  for (int jt = 0; jt < 2; ++jt)
#pragma unroll
    for (int su = 0; su < 4; ++su) {
      a2[jt][su][0] = 0.f; a2[jt][su][1] = 0.f;
      a2[jt][su][2] = 0.f; a2[jt][su][3] = 0.f;
    }

#pragma unroll
  for (int s = 0; s < 4; ++s) {
    __syncthreads();   // prior-stage readers done
    if (wo == (s >> 1)) {
#pragma unroll
      for (int u = 0; u < 4; ++u) {
        const int su1 = (s & 1) * 4 + u;
#pragma unroll
        for (int jt = 0; jt < 2; ++jt)
#pragma unroll
          for (int r = 0; r < 4; ++r) {
            const int j = jbase + jt * 16 + grp * 4 + r;
            float v = (a1[jt][su1][r] - mean1) * inv1;
            v = fmaxf(v, 0.01f * v);
            short h, l;
            split2(v, h, l);
            sH[j * CINP + u * 16 + col] = h;
            sL[j * CINP + u * 16 + col] = l;
          }
      }
    }
    __syncthreads();
#pragma unroll
    for (int kk = 0; kk < 3; ++kk)
#pragma unroll
      for (int q = 0; q < 2; ++q) {
        const int gks = kk * 8 + s * 2 + q;
        short8 ah[2], al[2];
#pragma unroll
        for (int jt = 0; jt < 2; ++jt) {
          const int ei = nbr[jt][kk] * CINP + q * 32 + grp * 8;
          ah[jt] = *reinterpret_cast<const short8*>(&sH[ei]);
          al[jt] = *reinterpret_cast<const short8*>(&sL[ei]);
        }
        short8 bh[4], bl[4];
#pragma unroll
        for (int su = 0; su < 4; ++su) {
          const int wi = ((gks * 2 + wo) * 4 + su) * 64 + lane;
          bh[su] = wp2h[wi];
          bl[su] = wp2l[wi];
        }
#pragma unroll
        for (int jt = 0; jt < 2; ++jt)
#pragma unroll
          for (int su = 0; su < 4; ++su) {
            a2[jt][su] = __builtin_amdgcn_mfma_f32_16x16x32_bf16(ah[jt], bh[su], a2[jt][su], 0, 0, 0);
            a2[jt][su] = __builtin_amdgcn_mfma_f32_16x16x32_bf16(al[jt], bh[su], a2[jt][su], 0, 0, 0);
            a2[jt][su] = __builtin_amdgcn_mfma_f32_16x16x32_bf16(ah[jt], bl[su], a2[jt][su], 0, 0, 0);
          }
      }
  }

  // ---- epilogue2 ----
  {
    double ss = 0.0, sq = 0.0;
#pragma unroll
    for (int su = 0; su < 4; ++su) {
      const float bv = b2[(wo * 4 + su) * 16 + col];
#pragma unroll
      for (int jt = 0; jt < 2; ++jt)
#pragma unroll
        for (int r = 0; r < 4; ++r) {
          const int j = jbase + jt * 16 + grp * 4 + r;
          const float val = (j > 0) ? a2[jt][su][r] + bv : 0.f;
          a2[jt][su][r] = val;
          ss += (double)val;
          sq += (double)val * (double)val;
        }
    }
    blockStats(ss, sq, 128.0 * 128.0);
  }
  const float mean2 = bc[0], inv2 = bc[1];

  // ---------------- conv3: COUT 64, SUB=2 ----------------
  f32x4 a3[2][2];
#pragma unroll
  for (int jt = 0; jt < 2; ++jt)
#pragma unroll
    for (int su = 0; su < 2; ++su) {
      a3[jt][su][0] = 0.f; a3[jt][su][1] = 0.f;
      a3[jt][su][2] = 0.f; a3[jt][su][3] = 0.f;
    }

#pragma unroll
  for (int s = 0; s < 2; ++s) {
    __syncthreads();
    if (wo == s) {
#pragma unroll
      for (int u = 0; u < 4; ++u) {
#pragma unroll
        for (int jt = 0; jt < 2; ++jt)
#pragma unroll
          for (int r = 0; r < 4; ++r) {
            const int j = jbase + jt * 16 + grp * 4 + r;
            float v = (a2[jt][u][r] - mean2) * inv2;
            v = fmaxf(v, 0.01f * v);
            short h, l;
            split2(v, h, l);
            sH[j * CINP + u * 16 + col] = h;
            sL[j * CINP + u * 16 + col] = l;
          }
      }
    }
    __syncthreads();
#pragma unroll
    for (int kk = 0; kk < 3; ++kk)
#pragma unroll
      for (int q = 0; q < 2; ++q) {
        const int gks = kk * 4 + s * 2 + q;
        short8 ah[2], al[2];
#pragma unroll
        for (int jt = 0; jt < 2; ++jt) {
          const int ei = nbr[jt][kk] * CINP + q * 32 + grp * 8;
          ah[jt] = *reinterpret_cast<const short8*>(&sH[ei]);
          al[jt] = *reinterpret_cast<const short8*>(&sL[ei]);
        }
        short8 bh[2], bl[2];
#pragma unroll
        for (int su = 0; su < 2; ++su) {
          const int wi = ((gks * 2 + wo) * 2 + su) * 64 + lane;
          bh[su] = wp3h[wi];
          bl[su] = wp3l[wi];
        }
#pragma unroll
        for (int jt = 0; jt < 2; ++jt)
#pragma unroll
          for (int su = 0; su < 2; ++su) {
            a3[jt][su] = __builtin_amdgcn_mfma_f32_16x16x32_bf16(ah[jt], bh[su], a3[jt][su], 0, 0, 0);
            a3[jt][su] = __builtin_amdgcn_mfma_f32_16x16x32_bf16(al[jt], bh[su], a3[jt][su], 0, 0, 0);
            a3[jt][su] = __builtin_amdgcn_mfma_f32_16x16x32_bf16(ah[jt], bl[su], a3[jt][su], 0, 0, 0);
          }
      }
  }

  // ---- epilogue3 + stats ----
  {
    double ss = 0.0, sq = 0.0;
#pragma unroll
    for (int su = 0; su < 2; ++su) {
      const float bv = b3[(wo * 2 + su) * 16 + col];
#pragma unroll
      for (int jt = 0; jt < 2; ++jt)
#pragma unroll
        for (int r = 0; r < 4; ++r) {
          const int j = jbase + jt * 16 + grp * 4 + r;
          const float val = (j > 0) ? a3[jt][su][r] + bv : 0.f;
          a3[jt][su][r] = val;
          ss += (double)val;
          sq += (double)val * (double)val;
        }
    }
    blockStats(ss, sq, 64.0 * 128.0);
  }
  const float mean3 = bc[0], inv3 = bc[1];

  // ---- maxpool over j (norm'd), then 2-layer MLP ----
#pragma unroll
  for (int su = 0; su < 2; ++su) {
    float pm = -3.4e38f;
#pragma unroll
    for (int jt = 0; jt < 2; ++jt)
#pragma unroll
      for (int r = 0; r < 4; ++r)
        pm = fmaxf(pm, (a3[jt][su][r] - mean3) * inv3);
    pm = fmaxf(pm, __shfl_xor(pm, 16, 64));
    pm = fmaxf(pm, __shfl_xor(pm, 32, 64));
    if (lane < 16) poolw[w][su * 16 + col] = pm;
  }
  __syncthreads();

  if (w == 0) {
    float hval = 0.f;
    if (lane < 32) {
      float a = fb1[lane];
#pragma unroll 8
      for (int c = 0; c < 64; ++c) {
        const int woc = c >> 5, loc = c & 31;
        float p = poolw[woc][loc];
#pragma unroll
        for (int jw = 1; jw < 4; ++jw) p = fmaxf(p, poolw[jw * 2 + woc][loc]);
        a = fmaf(p, fw1[lane * 64 + c], a);
      }
      hval = fmaxf(a, 0.f) * fw2[lane];
    }
#pragma unroll
    for (int o = 32; o > 0; o >>= 1) hval += __shfl_down(hval, o, 64);
    if (lane == 0) out[b] = hval + fb2[0];
  }
}

// ---------------------------------------------------------------------------
extern "C" void kernel_launch(void* const* d_in, const int* in_sizes, int n_in,
                              void* d_out, int out_size, void* d_ws, size_t ws_size,
                              hipStream_t stream) {
  const float* feature   = (const float*)d_in[0];
  const void*  indexes   = d_in[1];
  const float* col_embed = (const float*)d_in[2];
  const float* op_embed  = (const float*)d_in[3];
  const float* w1  = (const float*)d_in[4];
  const float* b1  = (const float*)d_in[5];
  const float* w2  = (const float*)d_in[6];
  const float* b2  = (const float*)d_in[7];
  const float* w3  = (const float*)d_in[8];
  const float* b3  = (const float*)d_in[9];
  const float* fw1 = (const float*)d_in[10];
  const float* fb1 = (const float*)d_in[11];
  const float* fw2 = (const float*)d_in[12];
  const float* fb2 = (const float*)d_in[13];
  float* out = (float*)d_out;

  char* ws = (char*)d_ws;
  size_t off = 0;
  auto carve = [&](size_t bytes) -> char* {
    off = (off + 255) & ~(size_t)255;
    char* p = ws + off;
    off += bytes;
    return p;
  };
  int*   idx32    = (int*)carve((size_t)S_IDX * sizeof(int));
  short* w1h      = (short*)carve((size_t)S_P1 * sizeof(short));
  short* w1l      = (short*)carve((size_t)S_P1 * sizeof(short));
  short* w2h      = (short*)carve((size_t)S_P2 * sizeof(short));
  short* w2l      = (short*)carve((size_t)S_P2 * sizeof(short));
  short* w3h      = (short*)carve((size_t)S_P3 * sizeof(short));
  short* w3l      = (short*)carve((size_t)S_P3 * sizeof(short));
  short* collateH = (short*)carve((size_t)B_ * 128 * KPAD1 * sizeof(short));
  short* collateL = (short*)carve((size_t)B_ * 128 * KPAD1 * sizeof(short));
  (void)ws_size; (void)in_sizes; (void)n_in; (void)out_size;

  hipLaunchKernelGGL(prep_embed_kernel, dim3(EMBED_BLOCKS + PREP_BLOCKS), dim3(512), 0, stream,
                     feature, col_embed, op_embed, collateH, collateL,
                     indexes, idx32, w1, w1h, w1l, w2, w2h, w2l, w3, w3h, w3l);
  hipLaunchKernelGGL(fused_kernel, dim3(B_), dim3(512), 0, stream,
                     collateH, collateL, idx32,
                     w1h, w1l, w2h, w2l, w3h, w3l,
                     b1, b2, b3, fw1, fb1, fw2, fb2, out);
}

// Round 14
// 84.235 us; speedup vs baseline: 2.6464x; 1.0217x over previous
//
#include <hip/hip_runtime.h>
#include <hip/hip_bf16.h>
#include <math.h>

// Problem constants (B, N, D) = (256, 128, 128)
#define B_    256
#define N_    128
#define MAXP  30
#define OTHER_ 35
#define CIN1  131
#define NIDX  381

#define KPAD1 160
#define KPAD2 256
#define KPAD3 128
#define S_IDX (B_ * NIDX)          // 97536
#define S_P1  (15 * 4 * 4 * 512)   // 122880  (gks * NWO4 * SUB4 * 512)
#define S_P2  (24 * 4 * 2 * 512)   // 98304
#define S_P3  (12 * 4 * 1 * 512)   // 24576
#define PREP_TOTAL (S_IDX + S_P1 + S_P2 + S_P3)
#define PREP_BLOCKS ((PREP_TOTAL + 511) / 512)
#define EMBED_BLOCKS (B_ * 4)

typedef short short8 __attribute__((ext_vector_type(8)));
typedef float f32x4 __attribute__((ext_vector_type(4)));

// RNE split of f32 into hi/lo bf16 via bit math (prep only)
__device__ inline void split1(float v, short& h, short& l) {
  unsigned u = __float_as_uint(v);
  unsigned hb = (u + 0x7fffu + ((u >> 16) & 1u)) >> 16;
  float fh = __uint_as_float(hb << 16);
  float r = v - fh;
  unsigned u2 = __float_as_uint(r);
  unsigned lb = (u2 + 0x7fffu + ((u2 >> 16) & 1u)) >> 16;
  h = (short)hb;
  l = (short)lb;
}

// RNE split via HW cvt — hot path
__device__ inline void split2(float v, short& h, short& l) {
  __hip_bfloat16 hb = __float2bfloat16(v);
  float fh = __bfloat162float(hb);
  __hip_bfloat16 lb = __float2bfloat16(v - fh);
  __builtin_memcpy(&h, &hb, 2);
  __builtin_memcpy(&l, &lb, 2);
}

// ---------------------------------------------------------------------------
// Weight pack: l -> [gks][g][su][lane][e]; g in [0,NWO). Value w[oc][ch][kk],
// oc=(g*SUB+su)*16+(lane&15), ctot=gks*32+((lane>>4)&3)*8+e,
// kk=ctot/KPAD, ch=ctot%KPAD (0 if ch>=KREAL).
// ---------------------------------------------------------------------------
template <int KREAL, int KPAD, int SUB, int NWO>
__device__ inline void packw(int l, const float* __restrict__ w,
                             short* __restrict__ oh, short* __restrict__ ol) {
  const int e = l & 7;
  const int lane = (l >> 3) & 63;
  const int x = l >> 9;
  const int su = x % SUB;
  const int y = x / SUB;
  const int g = y % NWO;
  const int gks = y / NWO;
  const int oc = (g * SUB + su) * 16 + (lane & 15);
  const int ctot = gks * 32 + ((lane >> 4) & 3) * 8 + e;
  const int kk = ctot / KPAD;
  const int ch = ctot - kk * KPAD;
  const float v = (ch < KREAL) ? w[(oc * KREAL + ch) * 3 + kk] : 0.f;
  short h, lo;
  split1(v, h, lo);
  oh[l] = h;
  ol[l] = lo;
}

// ---------------------------------------------------------------------------
// Merged prep + embed (as r13; NWO=4 pack factorization).
// ---------------------------------------------------------------------------
__global__ __launch_bounds__(512) void prep_embed_kernel(
    const float* __restrict__ feature,
    const float* __restrict__ col_embed,   // (200,32)
    const float* __restrict__ op_embed,    // (20,32)
    short* __restrict__ collateH, short* __restrict__ collateL,
    const void* __restrict__ rawIdx, int* __restrict__ idx32,
    const float* __restrict__ w1, short* __restrict__ w1h, short* __restrict__ w1l,
    const float* __restrict__ w2, short* __restrict__ w2h, short* __restrict__ w2l,
    const float* __restrict__ w3, short* __restrict__ w3h, short* __restrict__ w3l) {
  const int bx = blockIdx.x;
  const int tid = threadIdx.x;

  if (bx >= EMBED_BLOCKS) {
    const int gid = (bx - EMBED_BLOCKS) * 512 + tid;
    if (gid < S_IDX) {
      // int64 LE view is (v,0,v,0,...) with v in [0,128)
      const int* r32 = (const int*)rawIdx;
      const int lane = tid & 63;
      const int lo = r32[2 * lane];
      const int hi = r32[2 * lane + 1];
      const bool ok = (hi == 0 && lo >= 0 && lo < N_);
      const bool is64 = __all(ok);
      idx32[gid] = is64 ? (int)((const long long*)rawIdx)[gid] : ((const int*)rawIdx)[gid];
    } else if (gid < S_IDX + S_P1) {
      packw<131, KPAD1, 4, 4>(gid - S_IDX, w1, w1h, w1l);
    } else if (gid < S_IDX + S_P1 + S_P2) {
      packw<256, KPAD2, 2, 4>(gid - (S_IDX + S_P1), w2, w2h, w2l);
    } else if (gid < PREP_TOTAL) {
      packw<128, KPAD3, 1, 4>(gid - (S_IDX + S_P1 + S_P2), w3, w3h, w3l);
    }
    return;
  }

  __shared__ float feat[128 * 33];
  __shared__ float ce[200 * 32];
  __shared__ float oe[20 * 32];
  const int b = bx >> 2;
  const int n0 = (bx & 3) * 32;
  const float* fb = feature + (size_t)b * 16384;

  {
    const float4* s = (const float4*)col_embed;
    float4* d = (float4*)ce;
#pragma unroll
    for (int it = 0; it < 4; ++it) {
      const int t = it * 512 + tid;
      if (t < 1600) d[t] = s[t];
    }
    if (tid < 160) ((float4*)oe)[tid] = ((const float4*)op_embed)[tid];
  }
  {
    const int d = tid >> 2;
    const int c8 = (tid & 3) * 8;
    const float4 v0 = *reinterpret_cast<const float4*>(&fb[d * 128 + n0 + c8]);
    const float4 v1 = *reinterpret_cast<const float4*>(&fb[d * 128 + n0 + c8 + 4]);
    float* p = &feat[d * 33 + c8];
    p[0] = v0.x; p[1] = v0.y; p[2] = v0.z; p[3] = v0.w;
    p[4] = v1.x; p[5] = v1.y; p[6] = v1.z; p[7] = v1.w;
  }
  __syncthreads();

  const int wv = tid >> 6;
  const int lane = tid & 63;
  const int cl = lane & 31;

#pragma unroll
  for (int ni = 0; ni < 4; ++ni) {
    const int nl = wv * 4 + ni;
    const int n = n0 + nl;
    int civ = 0, oiv = 0;
    if (lane < MAXP) civ = (int)feat[(OTHER_ + lane) * 33 + nl];
    if (lane >= 32 && lane < 32 + MAXP) oiv = (int)feat[(OTHER_ + MAXP + (lane - 32)) * 33 + nl];
    const int L = (int)feat[95 * 33 + nl];

    float acc = 0.f;
    for (int i = 0; i < L; ++i) {
      const int cv = __shfl(civ, i);
      const int ov = __shfl(oiv, 32 + i);
      acc += (lane < 32) ? ce[cv * 32 + cl] : oe[ov * 32 + cl];
    }

    short* outH = collateH + ((size_t)b * 128 + n) * KPAD1;
    short* outL = collateL + ((size_t)b * 128 + n) * KPAD1;
    short h, l;
    split2(acc, h, l);
    outH[35 + lane] = h; outL[35 + lane] = l;
    if (lane < 35) {
      split2(feat[lane * 33 + nl], h, l);
      outH[lane] = h; outL[lane] = l;
    }
    if (lane < 32) {
      split2(feat[(96 + lane) * 33 + nl], h, l);
      outH[99 + lane] = h; outL[99 + lane] = l;
    }
    if (lane < 29) { outH[131 + lane] = 0; outL[131 + lane] = 0; }
  }
}

// ---------------------------------------------------------------------------
// FUSED v3: 1024 threads = 16 waves (wj 0..3 x wo 0..3), 4 waves/SIMD.
// Wave owns j in [wj*32,+32) (JT=2) and an oc-QUARTER (SUB = COUT/64).
// Full-layer LDS staging (CINP 264, sH+sL = 135 KB): one stage per layer,
// ~10 barriers total. Weight fragments read once per wo-quad (4x wj-reuse
// via L1). Inter-layer data: registers -> LDS (norm+leaky+split at write).
// Only global write: out[b].
// ---------------------------------------------------------------------------
__global__ __launch_bounds__(1024, 1) void fused_kernel(
    const short* __restrict__ XH, const short* __restrict__ XL,
    const int* __restrict__ idx,
    const short* __restrict__ w1h, const short* __restrict__ w1l,
    const short* __restrict__ w2h, const short* __restrict__ w2l,
    const short* __restrict__ w3h, const short* __restrict__ w3l,
    const float* __restrict__ b1, const float* __restrict__ b2,
    const float* __restrict__ b3,
    const float* __restrict__ fw1, const float* __restrict__ fb1,
    const float* __restrict__ fw2, const float* __restrict__ fb2,
    float* __restrict__ out) {
  constexpr int CINP = 264;   // shorts per row (33 granules of 8)

  __shared__ short sH[128 * CINP];   // 67.6 KB
  __shared__ short sL[128 * CINP];   // 67.6 KB
  __shared__ int nb_s[NIDX];
  __shared__ double red[32];
  __shared__ float bc[2];
  __shared__ float poolw[16][16];

  const int b = blockIdx.x;
  const int tid = threadIdx.x;
  const int lane = tid & 63;
  const int w = tid >> 6;       // 0..15
  const int wj = w >> 2;        // 0..3
  const int wo = w & 3;         // 0..3
  const int col = lane & 15;
  const int grp = (lane >> 4) & 3;
  const int jbase = wj * 32;

  const short8* __restrict__ wp1h = (const short8*)w1h;
  const short8* __restrict__ wp1l = (const short8*)w1l;
  const short8* __restrict__ wp2h = (const short8*)w2h;
  const short8* __restrict__ wp2l = (const short8*)w2l;
  const short8* __restrict__ wp3h = (const short8*)w3h;
  const short8* __restrict__ wp3l = (const short8*)w3l;

  auto blockStats = [&](double ss, double sq, double cnt) {
#pragma unroll
    for (int o = 32; o > 0; o >>= 1) {
      ss += __shfl_down(ss, o, 64);
      sq += __shfl_down(sq, o, 64);
    }
    if (lane == 0) { red[w * 2] = ss; red[w * 2 + 1] = sq; }
    __syncthreads();
    if (tid == 0) {
      double S = 0.0, Q = 0.0;
#pragma unroll
      for (int i = 0; i < 16; ++i) { S += red[i * 2]; Q += red[i * 2 + 1]; }
      const double m = S / cnt;
      double var = (Q - S * S / cnt) / (cnt - 1.0);
      if (var < 0.0) var = 0.0;
      bc[0] = (float)m;
      bc[1] = (float)(1.0 / (sqrt(var) + 1e-5));
    }
    __syncthreads();
  };

  // ---------------- conv1: stage full 160 ch (PURE copy) ----------------
  {
    const short* __restrict__ XHb = XH + (size_t)b * (128 * KPAD1);
    const short* __restrict__ XLb = XL + (size_t)b * (128 * KPAD1);
#pragma unroll
    for (int it = 0; it < 3; ++it) {
      const int t = it * 1024 + tid;
      if (t < 128 * 20) {                 // PKs = 160/8 = 20
        const int n = t / 20;
        const int c0 = (t - n * 20) * 8;
        *reinterpret_cast<short8*>(&sH[n * CINP + c0]) =
            *reinterpret_cast<const short8*>(&XHb[n * KPAD1 + c0]);
        *reinterpret_cast<short8*>(&sL[n * CINP + c0]) =
            *reinterpret_cast<const short8*>(&XLb[n * KPAD1 + c0]);
      }
    }
  }
  if (tid < NIDX) nb_s[tid] = idx[b * NIDX + tid];
  __syncthreads();

  int nbr[2][3];
#pragma unroll
  for (int jt = 0; jt < 2; ++jt) {
    const int jA = jbase + jt * 16 + col;
#pragma unroll
    for (int kk = 0; kk < 3; ++kk)
      nbr[jt][kk] = (jA > 0) ? nb_s[(jA - 1) * 3 + kk] : 0;
  }

  // ---------------- conv1 compute: COUT 256, SUB=4 ----------------
  f32x4 a1[2][4];
#pragma unroll
  for (int jt = 0; jt < 2; ++jt)
#pragma unroll
    for (int su = 0; su < 4; ++su) {
      a1[jt][su][0] = 0.f; a1[jt][su][1] = 0.f;
      a1[jt][su][2] = 0.f; a1[jt][su][3] = 0.f;
    }

#pragma unroll
  for (int kk = 0; kk < 3; ++kk) {
#pragma unroll
    for (int ks = 0; ks < 5; ++ks) {
      const int gks = kk * 5 + ks;
      short8 ah[2], al[2];
#pragma unroll
      for (int jt = 0; jt < 2; ++jt) {
        const int ei = nbr[jt][kk] * CINP + ks * 32 + grp * 8;
        ah[jt] = *reinterpret_cast<const short8*>(&sH[ei]);
        al[jt] = *reinterpret_cast<const short8*>(&sL[ei]);
      }
      short8 bh[4], bl[4];
#pragma unroll
      for (int su = 0; su < 4; ++su) {
        const int wi = ((gks * 4 + wo) * 4 + su) * 64 + lane;
        bh[su] = wp1h[wi];
        bl[su] = wp1l[wi];
      }
#pragma unroll
      for (int jt = 0; jt < 2; ++jt)
#pragma unroll
        for (int su = 0; su < 4; ++su) {
          a1[jt][su] = __builtin_amdgcn_mfma_f32_16x16x32_bf16(ah[jt], bh[su], a1[jt][su], 0, 0, 0);
          a1[jt][su] = __builtin_amdgcn_mfma_f32_16x16x32_bf16(al[jt], bh[su], a1[jt][su], 0, 0, 0);
          a1[jt][su] = __builtin_amdgcn_mfma_f32_16x16x32_bf16(ah[jt], bl[su], a1[jt][su], 0, 0, 0);
        }
    }
  }

  // ---- epilogue1: bias, zero col j=0, stats ----
  {
    double ss = 0.0, sq = 0.0;
#pragma unroll
    for (int su = 0; su < 4; ++su) {
      const float bv = b1[(wo * 4 + su) * 16 + col];
#pragma unroll
      for (int jt = 0; jt < 2; ++jt)
#pragma unroll
        for (int r = 0; r < 4; ++r) {
          const int j = jbase + jt * 16 + grp * 4 + r;
          const float val = (j > 0) ? a1[jt][su][r] + bv : 0.f;
          a1[jt][su][r] = val;
          ss += (double)val;
          sq += (double)val * (double)val;
        }
    }
    blockStats(ss, sq, 256.0 * 128.0);
  }
  const float mean1 = bc[0], inv1 = bc[1];

  // ---------------- conv2 stage: all 256 ch from registers ----------------
#pragma unroll
  for (int su = 0; su < 4; ++su) {
    const int c = (wo * 4 + su) * 16 + col;
#pragma unroll
    for (int jt = 0; jt < 2; ++jt)
#pragma unroll
      for (int r = 0; r < 4; ++r) {
        const int j = jbase + jt * 16 + grp * 4 + r;
        float v = (a1[jt][su][r] - mean1) * inv1;
        v = fmaxf(v, 0.01f * v);
        short h, l;
        split2(v, h, l);
        sH[j * CINP + c] = h;
        sL[j * CINP + c] = l;
      }
  }
  __syncthreads();

  // ---------------- conv2 compute: COUT 128, SUB=2 ----------------
  f32x4 a2[2][2];
#pragma unroll
  for (int jt = 0; jt < 2; ++jt)
#pragma unroll
    for (int su = 0; su < 2; ++su) {
      a2[jt][su][0] = 0.f; a2[jt][su][1] = 0.f;
      a2[jt][su][2] = 0.f; a2[jt][su][3] = 0.f;
    }

#pragma unroll
  for (int kk = 0; kk < 3; ++kk) {
#pragma unroll
    for (int ks = 0; ks < 8; ++ks) {
      const int gks = kk * 8 + ks;
      short8 ah[2], al[2];
#pragma unroll
      for (int jt = 0; jt < 2; ++jt) {
        const int ei = nbr[jt][kk] * CINP + ks * 32 + grp * 8;
        ah[jt] = *reinterpret_cast<const short8*>(&sH[ei]);
        al[jt] = *reinterpret_cast<const short8*>(&sL[ei]);
      }
      short8 bh[2], bl[2];
#pragma unroll
      for (int su = 0; su < 2; ++su) {
        const int wi = ((gks * 4 + wo) * 2 + su) * 64 + lane;
        bh[su] = wp2h[wi];
        bl[su] = wp2l[wi];
      }
#pragma unroll
      for (int jt = 0; jt < 2; ++jt)
#pragma unroll
        for (int su = 0; su < 2; ++su) {
          a2[jt][su] = __builtin_amdgcn_mfma_f32_16x16x32_bf16(ah[jt], bh[su], a2[jt][su], 0, 0, 0);
          a2[jt][su] = __builtin_amdgcn_mfma_f32_16x16x32_bf16(al[jt], bh[su], a2[jt][su], 0, 0, 0);
          a2[jt][su] = __builtin_amdgcn_mfma_f32_16x16x32_bf16(ah[jt], bl[su], a2[jt][su], 0, 0, 0);
        }
    }
  }

  // ---- epilogue2 ----
  {
    double ss = 0.0, sq = 0.0;
#pragma unroll
    for (int su = 0; su < 2; ++su) {
      const float bv = b2[(wo * 2 + su) * 16 + col];
#pragma unroll
      for (int jt = 0; jt < 2; ++jt)
#pragma unroll
        for (int r = 0; r < 4; ++r) {
          const int j = jbase + jt * 16 + grp * 4 + r;
          const float val = (j > 0) ? a2[jt][su][r] + bv : 0.f;
          a2[jt][su][r] = val;
          ss += (double)val;
          sq += (double)val * (double)val;
        }
    }
    blockStats(ss, sq, 128.0 * 128.0);
  }
  const float mean2 = bc[0], inv2 = bc[1];

  // ---------------- conv3 stage: all 128 ch ----------------
#pragma unroll
  for (int su = 0; su < 2; ++su) {
    const int c = (wo * 2 + su) * 16 + col;
#pragma unroll
    for (int jt = 0; jt < 2; ++jt)
#pragma unroll
      for (int r = 0; r < 4; ++r) {
        const int j = jbase + jt * 16 + grp * 4 + r;
        float v = (a2[jt][su][r] - mean2) * inv2;
        v = fmaxf(v, 0.01f * v);
        short h, l;
        split2(v, h, l);
        sH[j * CINP + c] = h;
        sL[j * CINP + c] = l;
      }
  }
  __syncthreads();

  // ---------------- conv3 compute: COUT 64, SUB=1 ----------------
  f32x4 a3[2];
#pragma unroll
  for (int jt = 0; jt < 2; ++jt) {
    a3[jt][0] = 0.f; a3[jt][1] = 0.f; a3[jt][2] = 0.f; a3[jt][3] = 0.f;
  }

#pragma unroll
  for (int kk = 0; kk < 3; ++kk) {
#pragma unroll
    for (int ks = 0; ks < 4; ++ks) {
      const int gks = kk * 4 + ks;
      short8 ah[2], al[2];
#pragma unroll
      for (int jt = 0; jt < 2; ++jt) {
        const int ei = nbr[jt][kk] * CINP + ks * 32 + grp * 8;
        ah[jt] = *reinterpret_cast<const short8*>(&sH[ei]);
        al[jt] = *reinterpret_cast<const short8*>(&sL[ei]);
      }
      short8 bh, bl;
      {
        const int wi = (gks * 4 + wo) * 64 + lane;
        bh = wp3h[wi];
        bl = wp3l[wi];
      }
#pragma unroll
      for (int jt = 0; jt < 2; ++jt) {
        a3[jt] = __builtin_amdgcn_mfma_f32_16x16x32_bf16(ah[jt], bh, a3[jt], 0, 0, 0);
        a3[jt] = __builtin_amdgcn_mfma_f32_16x16x32_bf16(al[jt], bh, a3[jt], 0, 0, 0);
        a3[jt] = __builtin_amdgcn_mfma_f32_16x16x32_bf16(ah[jt], bl, a3[jt], 0, 0, 0);
      }
    }
  }

  // ---- epilogue3 + stats ----
  {
    double ss = 0.0, sq = 0.0;
    const float bv = b3[wo * 16 + col];
#pragma unroll
    for (int jt = 0; jt < 2; ++jt)
#pragma unroll
      for (int r = 0; r < 4; ++r) {
        const int j = jbase + jt * 16 + grp * 4 + r;
        const float val = (j > 0) ? a3[jt][r] + bv : 0.f;
        a3[jt][r] = val;
        ss += (double)val;
        sq += (double)val * (double)val;
      }
    blockStats(ss, sq, 64.0 * 128.0);
  }
  const float mean3 = bc[0], inv3 = bc[1];

  // ---- maxpool over this wave's j-range, then cross-wj in LDS ----
  {
    float pm = -3.4e38f;
#pragma unroll
    for (int jt = 0; jt < 2; ++jt)
#pragma unroll
      for (int r = 0; r < 4; ++r)
        pm = fmaxf(pm, (a3[jt][r] - mean3) * inv3);
    pm = fmaxf(pm, __shfl_xor(pm, 16, 64));
    pm = fmaxf(pm, __shfl_xor(pm, 32, 64));
    if (lane < 16) poolw[w][col] = pm;
  }
  __syncthreads();

  // ---- 2-layer MLP (wave 0) ----
  if (w == 0) {
    float hval = 0.f;
    if (lane < 32) {
      float a = fb1[lane];
#pragma unroll 8
      for (int c = 0; c < 64; ++c) {
        const int oq = c >> 4, oc16 = c & 15;
        float p = poolw[oq][oc16];
#pragma unroll
        for (int jw = 1; jw < 4; ++jw) p = fmaxf(p, poolw[jw * 4 + oq][oc16]);
        a = fmaf(p, fw1[lane * 64 + c], a);
      }
      hval = fmaxf(a, 0.f) * fw2[lane];
    }
#pragma unroll
    for (int o = 32; o > 0; o >>= 1) hval += __shfl_down(hval, o, 64);
    if (lane == 0) out[b] = hval + fb2[0];
  }
}

// ---------------------------------------------------------------------------
extern "C" void kernel_launch(void* const* d_in, const int* in_sizes, int n_in,
                              void* d_out, int out_size, void* d_ws, size_t ws_size,
                              hipStream_t stream) {
  const float* feature   = (const float*)d_in[0];
  const void*  indexes   = d_in[1];
  const float* col_embed = (const float*)d_in[2];
  const float* op_embed  = (const float*)d_in[3];
  const float* w1  = (const float*)d_in[4];
  const float* b1  = (const float*)d_in[5];
  const float* w2  = (const float*)d_in[6];
  const float* b2  = (const float*)d_in[7];
  const float* w3  = (const float*)d_in[8];
  const float* b3  = (const float*)d_in[9];
  const float* fw1 = (const float*)d_in[10];
  const float* fb1 = (const float*)d_in[11];
  const float* fw2 = (const float*)d_in[12];
  const float* fb2 = (const float*)d_in[13];
  float* out = (float*)d_out;

  char* ws = (char*)d_ws;
  size_t off = 0;
  auto carve = [&](size_t bytes) -> char* {
    off = (off + 255) & ~(size_t)255;
    char* p = ws + off;
    off += bytes;
    return p;
  };
  int*   idx32    = (int*)carve((size_t)S_IDX * sizeof(int));
  short* w1h      = (short*)carve((size_t)S_P1 * sizeof(short));
  short* w1l      = (short*)carve((size_t)S_P1 * sizeof(short));
  short* w2h      = (short*)carve((size_t)S_P2 * sizeof(short));
  short* w2l      = (short*)carve((size_t)S_P2 * sizeof(short));
  short* w3h      = (short*)carve((size_t)S_P3 * sizeof(short));
  short* w3l      = (short*)carve((size_t)S_P3 * sizeof(short));
  short* collateH = (short*)carve((size_t)B_ * 128 * KPAD1 * sizeof(short));
  short* collateL = (short*)carve((size_t)B_ * 128 * KPAD1 * sizeof(short));
  (void)ws_size; (void)in_sizes; (void)n_in; (void)out_size;

  hipLaunchKernelGGL(prep_embed_kernel, dim3(EMBED_BLOCKS + PREP_BLOCKS), dim3(512), 0, stream,
                     feature, col_embed, op_embed, collateH, collateL,
                     indexes, idx32, w1, w1h, w1l, w2, w2h, w2l, w3, w3h, w3l);
  hipLaunchKernelGGL(fused_kernel, dim3(B_), dim3(1024), 0, stream,
                     collateH, collateL, idx32,
                     w1h, w1l, w2h, w2l, w3h, w3l,
                     b1, b2, b3, fw1, fb1, fw2, fb2, out);
}